// Round 3
// baseline (3179.864 us; speedup 1.0000x reference)
//
#include <hip/hip_runtime.h>
#include <hip/hip_bf16.h>

// GraphConv SpMM: out[row[e], :] += edge_vals[e] * x[col[e], :]
// N = 500000, E = 8000000, D = 64, fp32.
//
// Round 3: coarse bucket binning (bucket = row>>8, per-BLOCK contiguous run
// reservation to kill the 8x write-back amplification seen in round 2's
// per-row scatter) + per-bucket LDS accumulation (64 KB = 256 rows x 64 f32)
// with whole-wave-per-edge gathers (lane = feature -> 2-way LDS bank
// aliasing = free) and streaming float4 output stores.

#define D_FEAT 64
#define ROWS_PER_BKT 256
#define BKT_SHIFT 8            // bucket = row >> 8
#define MAX_BKT 2048
#define TILE_EDGES 8192
#define EDGES_PER_THREAD 32    // TILE_EDGES / 256

// ---------------- global bucket histogram (LDS-aggregated) ----------------
__global__ __launch_bounds__(256)
void hist_kernel(const int* __restrict__ row, int* __restrict__ cnt_g,
                 int n_edges, int kb) {
    __shared__ int cnt[MAX_BKT];
    for (int i = threadIdx.x; i < kb; i += 256) cnt[i] = 0;
    __syncthreads();
    int base = blockIdx.x * TILE_EDGES;
#pragma unroll
    for (int k = 0; k < EDGES_PER_THREAD; k++) {
        int e = base + k * 256 + threadIdx.x;
        if (e < n_edges) atomicAdd(&cnt[row[e] >> BKT_SHIFT], 1);
    }
    __syncthreads();
    for (int i = threadIdx.x; i < kb; i += 256) {
        int c = cnt[i];
        if (c) atomicAdd(&cnt_g[i], c);
    }
}

// ---------------- single-block scan over kb (<=2048) buckets --------------
__global__ __launch_bounds__(256)
void scan_kernel(const int* __restrict__ cnt_g, int* __restrict__ start,
                 int* __restrict__ gcursor, int kb) {
    __shared__ int sums[256];
    int vals[8];
    int base = threadIdx.x * 8;
    int s = 0;
#pragma unroll
    for (int i = 0; i < 8; i++) {
        int idx = base + i;
        int v = (idx < kb) ? cnt_g[idx] : 0;
        s += v;
        vals[i] = s;                       // inclusive within thread
    }
    sums[threadIdx.x] = s;
    __syncthreads();
    for (int off = 1; off < 256; off <<= 1) {
        int t = (threadIdx.x >= off) ? sums[threadIdx.x - off] : 0;
        __syncthreads();
        sums[threadIdx.x] += t;
        __syncthreads();
    }
    int toff = (threadIdx.x > 0) ? sums[threadIdx.x - 1] : 0;
#pragma unroll
    for (int i = 0; i < 8; i++) {
        int idx = base + i;
        if (idx < kb) {
            int incl = vals[i] + toff;
            int v = vals[i] - (i ? vals[i - 1] : 0);
            start[idx + 1] = incl;
            gcursor[idx] = incl - v;       // exclusive prefix = run base
        }
    }
    if (threadIdx.x == 0) start[0] = 0;
}

// ---------------- binning: per-block contiguous run reservation -----------
__global__ __launch_bounds__(256)
void bin_kernel(const int* __restrict__ row, const int* __restrict__ col,
                const float* __restrict__ val,
                int* __restrict__ gcursor, int2* __restrict__ packed,
                int n_edges, int kb) {
    __shared__ int cnt[MAX_BKT];
    __shared__ int base_s[MAX_BKT];
    for (int i = threadIdx.x; i < kb; i += 256) cnt[i] = 0;
    __syncthreads();
    int tbase = blockIdx.x * TILE_EDGES;
    int r_[EDGES_PER_THREAD];
#pragma unroll
    for (int k = 0; k < EDGES_PER_THREAD; k++) {
        int e = tbase + k * 256 + threadIdx.x;
        int r = (e < n_edges) ? row[e] : -1;
        r_[k] = r;
        if (r >= 0) atomicAdd(&cnt[r >> BKT_SHIFT], 1);
    }
    __syncthreads();
    for (int i = threadIdx.x; i < kb; i += 256) {
        int c = cnt[i];
        base_s[i] = c ? atomicAdd(&gcursor[i], c) : 0;  // one reservation/bucket
        cnt[i] = 0;                                     // reuse as rank cursor
    }
    __syncthreads();
#pragma unroll
    for (int k = 0; k < EDGES_PER_THREAD; k++) {
        int r = r_[k];
        if (r >= 0) {
            int e = tbase + k * 256 + threadIdx.x;
            int b = r >> BKT_SHIFT;
            int rank = atomicAdd(&cnt[b], 1);
            int pos = base_s[b] + rank;
            packed[pos] = make_int2(((r & (ROWS_PER_BKT - 1)) << 19) | col[e],
                                    __float_as_int(val[e]));
        }
    }
}

// ---------------- per-bucket LDS-accumulate reduce ------------------------
__global__ __launch_bounds__(512)
void reduce_kernel(const float* __restrict__ x, const int2* __restrict__ packed,
                   const int* __restrict__ start, float* __restrict__ out,
                   int n_nodes) {
    __shared__ float acc[ROWS_PER_BKT * D_FEAT];       // 64 KB
    float4* acc4 = (float4*)acc;
    for (int i = threadIdx.x; i < ROWS_PER_BKT * D_FEAT / 4; i += 512)
        acc4[i] = make_float4(0.f, 0.f, 0.f, 0.f);
    __syncthreads();

    int b = blockIdx.x;
    int s = start[b], e = start[b + 1];
    int wave = threadIdx.x >> 6;                       // 8 waves per block
    int lane = threadIdx.x & 63;                       // lane = feature index
    for (int i = s + wave; i < e; i += 8) {
        int2 rec = packed[i];                          // wave-uniform broadcast
        int lrow = ((unsigned)rec.x) >> 19;
        int c = rec.x & 0x7FFFF;
        float v = __int_as_float(rec.y);
        float xv = x[(size_t)c * D_FEAT + lane];       // 256B coalesced/wave
        atomicAdd(&acc[lrow * D_FEAT + lane], v * xv); // ds_add, 2-way banks
    }
    __syncthreads();

    int row0 = b * ROWS_PER_BKT;
    float4* out4 = (float4*)out;
    for (int i = threadIdx.x; i < ROWS_PER_BKT * D_FEAT / 4; i += 512) {
        if (row0 + (i >> 4) < n_nodes)
            out4[(size_t)row0 * (D_FEAT / 4) + i] = acc4[i];
    }
}

// ---------------- fallback (round-1 atomic version) -----------------------
__global__ __launch_bounds__(256)
void graphconv_scatter(const float* __restrict__ x, const float* __restrict__ edge_vals,
                       const int* __restrict__ row, const int* __restrict__ col,
                       float* __restrict__ out, int n_edges) {
    int tid = blockIdx.x * blockDim.x + threadIdx.x;
    int lane16 = tid & 15;
    int e = tid >> 4;
    if (e >= n_edges) return;
    int r = row[e];
    int c = col[e];
    float v = edge_vals[e];
    const float4* xs = (const float4*)(x + (size_t)c * D_FEAT);
    float4 xv = xs[lane16];
    float* o = out + (size_t)r * D_FEAT + lane16 * 4;
    atomicAdd(o + 0, v * xv.x);
    atomicAdd(o + 1, v * xv.y);
    atomicAdd(o + 2, v * xv.z);
    atomicAdd(o + 3, v * xv.w);
}

extern "C" void kernel_launch(void* const* d_in, const int* in_sizes, int n_in,
                              void* d_out, int out_size, void* d_ws, size_t ws_size,
                              hipStream_t stream) {
    const float* x         = (const float*)d_in[0];
    const float* edge_vals = (const float*)d_in[1];
    const int*   row       = (const int*)d_in[2];
    const int*   col       = (const int*)d_in[3];
    float* out = (float*)d_out;

    const int n_nodes = in_sizes[0] / D_FEAT;
    const int n_edges = in_sizes[1];
    const int kb = (n_nodes + ROWS_PER_BKT - 1) >> BKT_SHIFT;

    // ---- workspace layout ----
    size_t o_start  = 0;
    size_t o_cursor = ((size_t)(kb + 1) * 4 + 255) & ~size_t(255);
    size_t o_cnt    = o_cursor + (((size_t)kb * 4 + 255) & ~size_t(255));
    size_t o_packed = o_cnt + (((size_t)kb * 4 + 255) & ~size_t(255));
    size_t need     = o_packed + (size_t)n_edges * sizeof(int2);

    if (kb > MAX_BKT || n_nodes > (1 << 19) || need > ws_size) {
        // general fallback: pure-atomic scatter
        hipMemsetAsync(d_out, 0, (size_t)out_size * sizeof(float), stream);
        long long total_threads = (long long)n_edges * 16;
        int grid = (int)((total_threads + 255) / 256);
        graphconv_scatter<<<grid, 256, 0, stream>>>(x, edge_vals, row, col, out, n_edges);
        return;
    }

    char* wsb = (char*)d_ws;
    int*  start   = (int*)(wsb + o_start);
    int*  gcursor = (int*)(wsb + o_cursor);
    int*  cnt_g   = (int*)(wsb + o_cnt);
    int2* packed  = (int2*)(wsb + o_packed);

    const int nblksA = (n_edges + TILE_EDGES - 1) / TILE_EDGES;   // 977

    hipMemsetAsync(cnt_g, 0, (size_t)kb * sizeof(int), stream);
    hist_kernel<<<nblksA, 256, 0, stream>>>(row, cnt_g, n_edges, kb);
    scan_kernel<<<1, 256, 0, stream>>>(cnt_g, start, gcursor, kb);
    bin_kernel<<<nblksA, 256, 0, stream>>>(row, col, edge_vals, gcursor, packed,
                                           n_edges, kb);
    reduce_kernel<<<kb, 512, 0, stream>>>(x, packed, start, out, n_nodes);
}

// Round 4
// 832.444 us; speedup vs baseline: 3.8199x; 3.8199x over previous
//
#include <hip/hip_runtime.h>
#include <hip/hip_bf16.h>

// GraphConv SpMM: out[row[e], :] += edge_vals[e] * x[col[e], :]
// N = 500000, E = 8000000, D = 64, fp32.
//
// Round 4 pipeline:
//   1. bucket histogram (bucket = row>>8, 1954 buckets)
//   2. single-block scan -> bucket run starts
//   3. bin edges into bucket runs (per-BLOCK contiguous reservation ->
//      no write amplification; packs (lrow<<19 | col, val))
//   4. per-bucket LDS counting sort (in-place within the run) + emit
//      per-row row_start = run_base + local_prefix. Overflow (>CAP) buckets
//      stay unsorted, flag=0.
//   5. fine-grained reduce: 16 lanes per row, float4 gathers, 4-deep unroll,
//      full occupancy, plain float4 stores. Flagged buckets use a
//      scan-with-filter slow path (correctness insurance only).

#define D_FEAT 64
#define RPB 256                // rows per bucket
#define BKT_SHIFT 8
#define MAX_BKT 2048
#define TILE_EDGES 8192
#define EPT 32                 // edges per thread in hist/bin
#define CAP 6144               // max staged edges per bucket (mean 4096, sigma 64)

// ---------------- bucket histogram ----------------
__global__ __launch_bounds__(256)
void hist_kernel(const int* __restrict__ row, int* __restrict__ cnt_g,
                 int n_edges, int kb) {
    __shared__ int cnt[MAX_BKT];
    for (int i = threadIdx.x; i < kb; i += 256) cnt[i] = 0;
    __syncthreads();
    int base = blockIdx.x * TILE_EDGES;
#pragma unroll
    for (int k = 0; k < EPT; k++) {
        int e = base + k * 256 + threadIdx.x;
        if (e < n_edges) atomicAdd(&cnt[row[e] >> BKT_SHIFT], 1);
    }
    __syncthreads();
    for (int i = threadIdx.x; i < kb; i += 256) {
        int c = cnt[i];
        if (c) atomicAdd(&cnt_g[i], c);
    }
}

// ---------------- single-block scan over kb buckets ----------------
__global__ __launch_bounds__(256)
void scan_kernel(const int* __restrict__ cnt_g, int* __restrict__ start,
                 int* __restrict__ gcursor, int kb) {
    __shared__ int sums[256];
    int vals[8];
    int base = threadIdx.x * 8;
    int s = 0;
#pragma unroll
    for (int i = 0; i < 8; i++) {
        int idx = base + i;
        int v = (idx < kb) ? cnt_g[idx] : 0;
        s += v;
        vals[i] = s;
    }
    sums[threadIdx.x] = s;
    __syncthreads();
    for (int off = 1; off < 256; off <<= 1) {
        int t = (threadIdx.x >= off) ? sums[threadIdx.x - off] : 0;
        __syncthreads();
        sums[threadIdx.x] += t;
        __syncthreads();
    }
    int toff = (threadIdx.x > 0) ? sums[threadIdx.x - 1] : 0;
#pragma unroll
    for (int i = 0; i < 8; i++) {
        int idx = base + i;
        if (idx < kb) {
            int incl = vals[i] + toff;
            int v = vals[i] - (i ? vals[i - 1] : 0);
            start[idx + 1] = incl;
            gcursor[idx] = incl - v;
        }
    }
    if (threadIdx.x == 0) start[0] = 0;
}

// ---------------- bin edges into bucket runs ----------------
__global__ __launch_bounds__(256)
void bin_kernel(const int* __restrict__ row, const int* __restrict__ col,
                const float* __restrict__ val,
                int* __restrict__ gcursor, int2* __restrict__ packed,
                int n_edges, int kb) {
    __shared__ int cnt[MAX_BKT];
    __shared__ int base_s[MAX_BKT];
    for (int i = threadIdx.x; i < kb; i += 256) cnt[i] = 0;
    __syncthreads();
    int tbase = blockIdx.x * TILE_EDGES;
    int r_[EPT];
#pragma unroll
    for (int k = 0; k < EPT; k++) {
        int e = tbase + k * 256 + threadIdx.x;
        int r = (e < n_edges) ? row[e] : -1;
        r_[k] = r;
        if (r >= 0) atomicAdd(&cnt[r >> BKT_SHIFT], 1);
    }
    __syncthreads();
    for (int i = threadIdx.x; i < kb; i += 256) {
        int c = cnt[i];
        base_s[i] = c ? atomicAdd(&gcursor[i], c) : 0;
        cnt[i] = 0;
    }
    __syncthreads();
#pragma unroll
    for (int k = 0; k < EPT; k++) {
        int r = r_[k];
        if (r >= 0) {
            int e = tbase + k * 256 + threadIdx.x;
            int b = r >> BKT_SHIFT;
            int rank = atomicAdd(&cnt[b], 1);
            packed[base_s[b] + rank] =
                make_int2(((r & (RPB - 1)) << 19) | col[e], __float_as_int(val[e]));
        }
    }
}

// ---------------- per-bucket counting sort (in place) ----------------
__global__ __launch_bounds__(256)
void sort_kernel(int2* __restrict__ packed, const int* __restrict__ start,
                 int* __restrict__ row_start, int* __restrict__ flags,
                 int n_nodes, int n_edges) {
    __shared__ int2 ed[CAP];          // 48 KB
    __shared__ int cnt[256];
    __shared__ int sc[256];
    __shared__ int cur[256];

    int b = blockIdx.x;
    int tid = threadIdx.x;
    int s = start[b], e = start[b + 1];
    int n = e - s;

    cnt[tid] = 0;
    __syncthreads();

    if (n <= CAP) {
        for (int i = tid; i < n; i += 256) {
            int2 r = packed[s + i];
            ed[i] = r;
            atomicAdd(&cnt[((unsigned)r.x) >> 19], 1);
        }
    } else {
        for (int i = tid; i < n; i += 256)
            atomicAdd(&cnt[((unsigned)packed[s + i].x) >> 19], 1);
    }
    __syncthreads();

    // inclusive scan of cnt -> sc
    sc[tid] = cnt[tid];
    __syncthreads();
    for (int off = 1; off < 256; off <<= 1) {
        int t = (tid >= off) ? sc[tid - off] : 0;
        __syncthreads();
        sc[tid] += t;
        __syncthreads();
    }
    int excl = (tid > 0) ? sc[tid - 1] : 0;
    cur[tid] = excl;

    // per-row starts (global)
    int gr = b * RPB + tid;
    if (gr < n_nodes) row_start[gr] = s + excl;
    if (b == 0 && tid == 0) row_start[n_nodes] = n_edges;
    __syncthreads();

    if (n <= CAP) {
        for (int i = tid; i < n; i += 256) {
            int2 r = ed[i];
            int d = atomicAdd(&cur[((unsigned)r.x) >> 19], 1);
            packed[s + d] = r;           // in-place: all reads staged to LDS
        }
        if (tid == 0) flags[b] = 1;
    }
    // overflow: leave unsorted, flags[b] stays 0
}

// ---------------- fine-grained reduce ----------------
__global__ __launch_bounds__(256)
void reduce_csr(const float* __restrict__ x, const int2* __restrict__ packed,
                const int* __restrict__ row_start, const int* __restrict__ start,
                const int* __restrict__ flags, float* __restrict__ out,
                int n_nodes) {
    int tid = blockIdx.x * blockDim.x + threadIdx.x;
    int lane = tid & 15;
    int r = tid >> 4;
    if (r >= n_nodes) return;

    const float4* x4 = (const float4*)x;
    float4 acc = {0.f, 0.f, 0.f, 0.f};

    if (__builtin_expect(flags[r >> BKT_SHIFT], 1)) {
        int s = row_start[r];
        int e = row_start[r + 1];
        int i = s;
        for (; i + 3 < e; i += 4) {
            int2 a0 = packed[i], a1 = packed[i + 1], a2 = packed[i + 2], a3 = packed[i + 3];
            float4 x0 = x4[(size_t)(a0.x & 0x7FFFF) * 16 + lane];
            float4 x1 = x4[(size_t)(a1.x & 0x7FFFF) * 16 + lane];
            float4 x2 = x4[(size_t)(a2.x & 0x7FFFF) * 16 + lane];
            float4 x3 = x4[(size_t)(a3.x & 0x7FFFF) * 16 + lane];
            float v0 = __int_as_float(a0.y), v1 = __int_as_float(a1.y);
            float v2 = __int_as_float(a2.y), v3 = __int_as_float(a3.y);
            acc.x += v0 * x0.x; acc.y += v0 * x0.y; acc.z += v0 * x0.z; acc.w += v0 * x0.w;
            acc.x += v1 * x1.x; acc.y += v1 * x1.y; acc.z += v1 * x1.z; acc.w += v1 * x1.w;
            acc.x += v2 * x2.x; acc.y += v2 * x2.y; acc.z += v2 * x2.z; acc.w += v2 * x2.w;
            acc.x += v3 * x3.x; acc.y += v3 * x3.y; acc.z += v3 * x3.z; acc.w += v3 * x3.w;
        }
        for (; i < e; i++) {
            int2 a0 = packed[i];
            float4 x0 = x4[(size_t)(a0.x & 0x7FFFF) * 16 + lane];
            float v0 = __int_as_float(a0.y);
            acc.x += v0 * x0.x; acc.y += v0 * x0.y; acc.z += v0 * x0.z; acc.w += v0 * x0.w;
        }
    } else {
        // unsorted bucket: scan run with row filter (correctness path)
        int b = r >> BKT_SHIFT;
        int lr = r & (RPB - 1);
        int s = start[b], e = start[b + 1];
        for (int i = s; i < e; i++) {
            int2 a0 = packed[i];
            if ((int)(((unsigned)a0.x) >> 19) == lr) {
                float4 x0 = x4[(size_t)(a0.x & 0x7FFFF) * 16 + lane];
                float v0 = __int_as_float(a0.y);
                acc.x += v0 * x0.x; acc.y += v0 * x0.y; acc.z += v0 * x0.z; acc.w += v0 * x0.w;
            }
        }
    }
    ((float4*)out)[(size_t)r * 16 + lane] = acc;
}

// ---------------- fallback (round-1 atomic version) ----------------
__global__ __launch_bounds__(256)
void graphconv_scatter(const float* __restrict__ x, const float* __restrict__ edge_vals,
                       const int* __restrict__ row, const int* __restrict__ col,
                       float* __restrict__ out, int n_edges) {
    int tid = blockIdx.x * blockDim.x + threadIdx.x;
    int lane16 = tid & 15;
    int e = tid >> 4;
    if (e >= n_edges) return;
    int r = row[e];
    int c = col[e];
    float v = edge_vals[e];
    const float4* xs = (const float4*)(x + (size_t)c * D_FEAT);
    float4 xv = xs[lane16];
    float* o = out + (size_t)r * D_FEAT + lane16 * 4;
    atomicAdd(o + 0, v * xv.x);
    atomicAdd(o + 1, v * xv.y);
    atomicAdd(o + 2, v * xv.z);
    atomicAdd(o + 3, v * xv.w);
}

extern "C" void kernel_launch(void* const* d_in, const int* in_sizes, int n_in,
                              void* d_out, int out_size, void* d_ws, size_t ws_size,
                              hipStream_t stream) {
    const float* x         = (const float*)d_in[0];
    const float* edge_vals = (const float*)d_in[1];
    const int*   row       = (const int*)d_in[2];
    const int*   col       = (const int*)d_in[3];
    float* out = (float*)d_out;

    const int n_nodes = in_sizes[0] / D_FEAT;
    const int n_edges = in_sizes[1];
    const int kb = (n_nodes + RPB - 1) >> BKT_SHIFT;

    // ---- workspace layout ----
    size_t off = 0;
    auto alloc = [&](size_t bytes) {
        size_t p = off;
        off += (bytes + 255) & ~size_t(255);
        return p;
    };
    size_t o_start    = alloc((size_t)(kb + 1) * sizeof(int));
    size_t o_gcursor  = alloc((size_t)kb * sizeof(int));
    size_t o_cntflags = alloc((size_t)(2 * kb) * sizeof(int));  // cnt_g | flags
    size_t o_rowstart = alloc((size_t)(n_nodes + 1) * sizeof(int));
    size_t o_packed   = alloc((size_t)n_edges * sizeof(int2));

    if (kb > MAX_BKT || n_nodes > (1 << 19) || off > ws_size) {
        hipMemsetAsync(d_out, 0, (size_t)out_size * sizeof(float), stream);
        long long total_threads = (long long)n_edges * 16;
        int grid = (int)((total_threads + 255) / 256);
        graphconv_scatter<<<grid, 256, 0, stream>>>(x, edge_vals, row, col, out, n_edges);
        return;
    }

    char* wsb = (char*)d_ws;
    int*  start     = (int*)(wsb + o_start);
    int*  gcursor   = (int*)(wsb + o_gcursor);
    int*  cnt_g     = (int*)(wsb + o_cntflags);
    int*  flags     = cnt_g + kb;
    int*  row_start = (int*)(wsb + o_rowstart);
    int2* packed    = (int2*)(wsb + o_packed);

    const int nblksA = (n_edges + TILE_EDGES - 1) / TILE_EDGES;

    hipMemsetAsync(cnt_g, 0, (size_t)(2 * kb) * sizeof(int), stream);
    hist_kernel<<<nblksA, 256, 0, stream>>>(row, cnt_g, n_edges, kb);
    scan_kernel<<<1, 256, 0, stream>>>(cnt_g, start, gcursor, kb);
    bin_kernel<<<nblksA, 256, 0, stream>>>(row, col, edge_vals, gcursor, packed,
                                           n_edges, kb);
    sort_kernel<<<kb, 256, 0, stream>>>(packed, start, row_start, flags,
                                        n_nodes, n_edges);
    long long rthreads = (long long)n_nodes * 16;
    reduce_csr<<<(int)((rthreads + 255) / 256), 256, 0, stream>>>(
        x, packed, row_start, start, flags, out, n_nodes);
}